// Round 1
// baseline (305.085 us; speedup 1.0000x reference)
//
#include <hip/hip_runtime.h>
#include <hip/hip_bf16.h>

#define DM 512
#define HEADS 8
#define DEPTH 64
#define BATCH 4
#define SEQ 8192
#define MROWS (BATCH*SEQ)

using short8 = __attribute__((ext_vector_type(8))) short;
using floatx4 = __attribute__((ext_vector_type(4))) float;

static __device__ __forceinline__ float bf2f(unsigned short u) {
    union { unsigned int i; float f; } x; x.i = ((unsigned int)u) << 16; return x.f;
}
static __device__ __forceinline__ unsigned short f2bf(float f) {
    union { float f; unsigned int i; } x; x.f = f;
    unsigned int i = x.i;
    return (unsigned short)((i + 0x7FFFu + ((i >> 16) & 1u)) >> 16);
}

// ---- W prep: transpose + convert to bf16. wT[n][k] = w[k][n] ----
__global__ __launch_bounds__(256) void wprep_kernel(const float* __restrict__ w,
                                                    unsigned short* __restrict__ wT) {
    int idx = blockIdx.x * 256 + threadIdx.x;
    int k = idx & (DM - 1);
    int n = idx >> 9;
    wT[n * DM + k] = f2bf(w[k * DM + n]);
}

// ---- Projection GEMM: Y[m][n] = phi?(X[m][:] @ W[:][n] + bias[n]) as bf16 ----
// 128x128 tile, BK=32, 4 waves (2x2), each wave 64x64 via 4x4 mfma_f32_16x16x32_bf16.
template<int PHI>
__global__ __launch_bounds__(256) void proj_kernel(const float* __restrict__ X,
                                                   const unsigned short* __restrict__ WT,
                                                   const float* __restrict__ bias,
                                                   unsigned short* __restrict__ Y) {
    __shared__ unsigned short As[128][40];   // 32 k + 8 pad (80B rows -> <=2-way bank alias)
    __shared__ unsigned short Bs[128][40];   // [n][k], from pre-transposed W

    const int t = threadIdx.x;
    const int l = t & 63;
    const int w = t >> 6;
    const int m0 = blockIdx.y * 128;
    const int n0 = blockIdx.x * 128;
    const int wr = (w >> 1) * 64;
    const int wc = (w & 1) * 64;
    const int l15 = l & 15;
    const int g = l >> 4;

    floatx4 acc[4][4] = {};

    for (int k0 = 0; k0 < DM; k0 += 32) {
        // stage A: 128x32 fp32 -> bf16 LDS (1024 float4, 4 per thread)
        #pragma unroll
        for (int j = 0; j < 4; ++j) {
            int f = t + 256 * j;
            int row = f >> 3, c4 = f & 7;
            const float4 v = *(const float4*)(X + (size_t)(m0 + row) * DM + k0 + c4 * 4);
            unsigned int lo = (unsigned int)f2bf(v.x) | ((unsigned int)f2bf(v.y) << 16);
            unsigned int hi = (unsigned int)f2bf(v.z) | ((unsigned int)f2bf(v.w) << 16);
            *(uint2*)&As[row][c4 * 4] = make_uint2(lo, hi);
        }
        // stage B: 128x32 bf16 (512 x 16B pieces, 2 per thread)
        #pragma unroll
        for (int j = 0; j < 2; ++j) {
            int f = t + 256 * j;
            int n = f >> 2, p = f & 3;
            *(int4*)&Bs[n][p * 8] = *(const int4*)(WT + (size_t)(n0 + n) * DM + k0 + p * 8);
        }
        __syncthreads();

        short8 a[4], bq[4];
        #pragma unroll
        for (int m = 0; m < 4; ++m) a[m] = *(const short8*)&As[wr + m * 16 + l15][g * 8];
        #pragma unroll
        for (int n = 0; n < 4; ++n) bq[n] = *(const short8*)&Bs[wc + n * 16 + l15][g * 8];
        #pragma unroll
        for (int m = 0; m < 4; ++m)
            #pragma unroll
            for (int n = 0; n < 4; ++n)
                acc[m][n] = __builtin_amdgcn_mfma_f32_16x16x32_bf16(a[m], bq[n], acc[m][n], 0, 0, 0);
        __syncthreads();
    }

    // epilogue: C/D layout col=lane&15, row=(lane>>4)*4+reg  [verified m89/m91]
    #pragma unroll
    for (int n = 0; n < 4; ++n) {
        int col = n0 + wc + n * 16 + l15;
        float bv = bias[col];
        #pragma unroll
        for (int m = 0; m < 4; ++m) {
            #pragma unroll
            for (int j = 0; j < 4; ++j) {
                int row = m0 + wr + m * 16 + g * 4 + j;
                float v = acc[m][n][j] + bv;
                if (PHI) v = (v > 0.0f) ? (v + 1.0f) : __expf(v);  // elu(x)+1
                Y[(size_t)row * DM + col] = f2bf(v);
            }
        }
    }
}

// ---- kv einsum + k_red: KV[b,h][d][e] = sum_s kh[b,s,h,d]*vh[b,s,h,e] ----
// block = (s-chunk 512, h, b); split-K partials accumulated via fp32 atomics.
__global__ __launch_bounds__(256) void kv_kernel(const unsigned short* __restrict__ kh,
                                                 const unsigned short* __restrict__ vh,
                                                 float* __restrict__ kv,
                                                 float* __restrict__ kred) {
    __shared__ float khs[32][64];
    __shared__ float vhs[32][64];
    const int t = threadIdx.x;
    const int b = blockIdx.z, h = blockIdx.y;
    const int s0 = blockIdx.x * 512;
    const int d0 = (t >> 4) * 4;
    const int e0 = (t & 15) * 4;

    float acc[4][4] = {};
    float kr[4] = {};

    const size_t rowbase = (size_t)b * SEQ * DM + h * DEPTH;

    for (int sc = 0; sc < 512; sc += 32) {
        int s_i = t >> 3, p = t & 7;
        size_t off = rowbase + (size_t)(s0 + sc + s_i) * DM + p * 8;
        int4 kraw = *(const int4*)(kh + off);
        int4 vraw = *(const int4*)(vh + off);
        const unsigned short* kk = (const unsigned short*)&kraw;
        const unsigned short* vv = (const unsigned short*)&vraw;
        __syncthreads();  // all prior-iteration LDS reads complete
        #pragma unroll
        for (int q = 0; q < 8; ++q) khs[s_i][p * 8 + q] = bf2f(kk[q]);
        #pragma unroll
        for (int q = 0; q < 8; ++q) vhs[s_i][p * 8 + q] = bf2f(vv[q]);
        __syncthreads();
        #pragma unroll 8
        for (int si = 0; si < 32; ++si) {
            float4 k4 = *(const float4*)&khs[si][d0];   // broadcast within 16-lane group
            float4 v4 = *(const float4*)&vhs[si][e0];
            float ka[4] = {k4.x, k4.y, k4.z, k4.w};
            float va[4] = {v4.x, v4.y, v4.z, v4.w};
            #pragma unroll
            for (int i = 0; i < 4; ++i) kr[i] += ka[i];
            #pragma unroll
            for (int i = 0; i < 4; ++i)
                #pragma unroll
                for (int j = 0; j < 4; ++j)
                    acc[i][j] += ka[i] * va[j];
        }
    }
    float* kvp = kv + (size_t)(b * HEADS + h) * (DEPTH * DEPTH);
    #pragma unroll
    for (int i = 0; i < 4; ++i)
        #pragma unroll
        for (int j = 0; j < 4; ++j)
            atomicAdd(&kvp[(d0 + i) * DEPTH + e0 + j], acc[i][j]);
    if (e0 == 0) {
        float* krp = kred + (b * HEADS + h) * DEPTH;
        #pragma unroll
        for (int i = 0; i < 4; ++i) atomicAdd(&krp[d0 + i], kr[i]);
    }
}

// ---- out: out[b,s,h,e] = (sum_d qh_d * KV[d][e]) / (sum_d qh_d * (kred_d+eps)) ----
__global__ __launch_bounds__(256) void out_kernel(const unsigned short* __restrict__ qh,
                                                  const float* __restrict__ kv,
                                                  const float* __restrict__ kred,
                                                  float* __restrict__ out) {
    __shared__ float kvs[DEPTH * DEPTH];
    __shared__ float krs[DEPTH];
    const int t = threadIdx.x;
    const int b = blockIdx.z, h = blockIdx.y;
    const int s = blockIdx.x * 256 + t;

    const float* kvp = kv + (size_t)(b * HEADS + h) * (DEPTH * DEPTH);
    #pragma unroll
    for (int j = 0; j < 4; ++j) {
        int f = t + 256 * j;
        *(float4*)&kvs[f * 4] = *(const float4*)&kvp[f * 4];
    }
    if (t < DEPTH) krs[t] = kred[(b * HEADS + h) * DEPTH + t] + 1e-8f;
    __syncthreads();

    const size_t qoff = ((size_t)b * SEQ + s) * DM + h * DEPTH;
    float4 acc[16] = {};
    float den = 0.0f;
    for (int dblk = 0; dblk < 8; ++dblk) {
        int4 qraw = *(const int4*)(qh + qoff + dblk * 8);
        const unsigned short* qq = (const unsigned short*)&qraw;
        #pragma unroll
        for (int dd = 0; dd < 8; ++dd) {
            int d = dblk * 8 + dd;
            float qd = bf2f(qq[dd]);
            den += qd * krs[d];
            #pragma unroll
            for (int e4 = 0; e4 < 16; ++e4) {
                float4 kvv = *(const float4*)&kvs[d * 64 + e4 * 4];  // uniform -> LDS broadcast
                acc[e4].x += qd * kvv.x; acc[e4].y += qd * kvv.y;
                acc[e4].z += qd * kvv.z; acc[e4].w += qd * kvv.w;
            }
        }
    }
    float z = 1.0f / den;
    float* op = out + qoff;
    #pragma unroll
    for (int e4 = 0; e4 < 16; ++e4) {
        float4 v = acc[e4];
        v.x *= z; v.y *= z; v.z *= z; v.w *= z;
        *(float4*)(op + e4 * 4) = v;
    }
}

extern "C" void kernel_launch(void* const* d_in, const int* in_sizes, int n_in,
                              void* d_out, int out_size, void* d_ws, size_t ws_size,
                              hipStream_t stream) {
    const float* q  = (const float*)d_in[0];
    const float* k  = (const float*)d_in[1];
    const float* v  = (const float*)d_in[2];
    const float* wq = (const float*)d_in[3];
    const float* bq = (const float*)d_in[4];
    const float* wk = (const float*)d_in[5];
    const float* bk = (const float*)d_in[6];
    const float* wv = (const float*)d_in[7];
    const float* bv = (const float*)d_in[8];
    float* out = (float*)d_out;

    char* ws = (char*)d_ws;
    const size_t sz_h = (size_t)MROWS * DM * 2;                 // 32 MiB each (bf16)
    unsigned short* qh  = (unsigned short*)(ws);
    unsigned short* kh  = (unsigned short*)(ws + sz_h);
    unsigned short* vh  = (unsigned short*)(ws + 2 * sz_h);
    unsigned short* wqT = (unsigned short*)(ws + 3 * sz_h);
    unsigned short* wkT = wqT + DM * DM;
    unsigned short* wvT = wkT + DM * DM;
    float* kvbuf   = (float*)(ws + 3 * sz_h + (size_t)3 * DM * DM * 2);
    float* kredbuf = kvbuf + BATCH * HEADS * DEPTH * DEPTH;

    hipMemsetAsync(kvbuf, 0,
                   (size_t)(BATCH * HEADS * DEPTH * DEPTH + BATCH * HEADS * DEPTH) * sizeof(float),
                   stream);

    wprep_kernel<<<dim3(DM * DM / 256), 256, 0, stream>>>(wq, wqT);
    wprep_kernel<<<dim3(DM * DM / 256), 256, 0, stream>>>(wk, wkT);
    wprep_kernel<<<dim3(DM * DM / 256), 256, 0, stream>>>(wv, wvT);

    dim3 pgrid(DM / 128, MROWS / 128);
    proj_kernel<1><<<pgrid, 256, 0, stream>>>(q, wqT, bq, qh);
    proj_kernel<1><<<pgrid, 256, 0, stream>>>(k, wkT, bk, kh);
    proj_kernel<0><<<pgrid, 256, 0, stream>>>(v, wvT, bv, vh);

    kv_kernel<<<dim3(16, HEADS, BATCH), 256, 0, stream>>>(kh, vh, kvbuf, kredbuf);
    out_kernel<<<dim3(SEQ / 256, HEADS, BATCH), 256, 0, stream>>>(qh, kvbuf, kredbuf, out);
}

// Round 2
// 262.337 us; speedup vs baseline: 1.1629x; 1.1629x over previous
//
#include <hip/hip_runtime.h>
#include <hip/hip_bf16.h>

#define DM 512
#define HEADS 8
#define DEPTH 64
#define BATCH 4
#define SEQ 8192
#define MROWS (BATCH*SEQ)

using short8 = __attribute__((ext_vector_type(8))) short;
using floatx4 = __attribute__((ext_vector_type(4))) float;

#define AS1 __attribute__((address_space(1)))
#define AS3 __attribute__((address_space(3)))

static __device__ __forceinline__ float bf2f(unsigned short u) {
    union { unsigned int i; float f; } x; x.i = ((unsigned int)u) << 16; return x.f;
}
static __device__ __forceinline__ unsigned short f2bf(float f) {
    union { float f; unsigned int i; } x; x.f = f;
    unsigned int i = x.i;
    return (unsigned short)((i + 0x7FFFu + ((i >> 16) & 1u)) >> 16);
}
static __device__ __forceinline__ void gl_lds16(const unsigned short* g, unsigned short* l) {
    __builtin_amdgcn_global_load_lds((const AS1 unsigned int*)g, (AS3 unsigned int*)l, 16, 0, 0);
}

// ---- W prep: transpose + convert to bf16. wT[n][k] = w[k][n] ----
__global__ __launch_bounds__(256) void wprep_kernel(const float* __restrict__ w,
                                                    unsigned short* __restrict__ wT) {
    int idx = blockIdx.x * 256 + threadIdx.x;
    int k = idx & (DM - 1);
    int n = idx >> 9;
    wT[n * DM + k] = f2bf(w[k * DM + n]);
}

// ---- Projection GEMM: Y[m][n] = phi?(X @ W + bias) as bf16 ----
// Tile 64(M) x 256(N), BK=64, 4 waves: wave w owns cols [w*64, w*64+64), all 64 rows.
// A: fp32 global -> reg -> cvt bf16 -> padded LDS [64][72]  (bank-uniform, verified)
// B: bf16 WT via global_load_lds, linear LDS [256][64] with data chunk-XOR-swizzled
//    (chunk' = chunk ^ (row&7)) on the GLOBAL source; reads apply same XOR -> 2-way/free.
template<int PHI>
__global__ __launch_bounds__(256) void proj_kernel(const float* __restrict__ X,
                                                   const unsigned short* __restrict__ WT,
                                                   const float* __restrict__ bias,
                                                   unsigned short* __restrict__ Y) {
    __shared__ unsigned short As[64][72];      // 9 KiB (144 B rows)
    __shared__ unsigned short Bs[256 * 64];    // 32 KiB (128 B rows, swizzled contents)

    const int t = threadIdx.x;
    const int l = t & 63;
    const int w = t >> 6;
    const int l15 = l & 15;
    const int g = l >> 4;
    const int m0 = blockIdx.y * 64;
    const int n0 = blockIdx.x * 256;
    const int wc = w * 64;

    // A staging: thread covers chunks t and 256+t (8 floats each)
    const int arow0 = t >> 3;
    const int arow1 = 32 + (t >> 3);
    const int acol = (t & 7) * 8;
    const float* xp0 = X + (size_t)(m0 + arow0) * DM + acol;
    const float* xp1 = X + (size_t)(m0 + arow1) * DM + acol;

    floatx4 acc[4][4] = {};

    for (int k0 = 0; k0 < DM; k0 += 64) {
        // issue A global loads early (regs only; overlaps prior MFMA phase)
        const float4 av0 = *(const float4*)(xp0 + k0);
        const float4 av1 = *(const float4*)(xp0 + k0 + 4);
        const float4 av2 = *(const float4*)(xp1 + k0);
        const float4 av3 = *(const float4*)(xp1 + k0 + 4);

        __syncthreads();   // prior iteration's LDS reads complete

        // B: 8 x global_load_lds (16B/lane). LDS linear; global source pre-swizzled.
        #pragma unroll
        for (int i = 0; i < 8; ++i) {
            int c = i * 256 + t;             // 16B chunk index in [256][64] tile
            int r = c >> 3;
            int gp = c & 7;
            int gd = gp ^ (r & 7);           // data chunk stored at position gp
            const unsigned short* gsrc = WT + (size_t)(n0 + r) * DM + k0 + gd * 8;
            unsigned short* ldst = Bs + ((size_t)i * 256 + w * 64) * 8; // wave-uniform base
            gl_lds16(gsrc, ldst);
        }

        // A: convert 16 fp32 -> bf16, two b128 LDS writes
        {
            unsigned int p0 = (unsigned int)f2bf(av0.x) | ((unsigned int)f2bf(av0.y) << 16);
            unsigned int p1 = (unsigned int)f2bf(av0.z) | ((unsigned int)f2bf(av0.w) << 16);
            unsigned int p2 = (unsigned int)f2bf(av1.x) | ((unsigned int)f2bf(av1.y) << 16);
            unsigned int p3 = (unsigned int)f2bf(av1.z) | ((unsigned int)f2bf(av1.w) << 16);
            *(uint4*)&As[arow0][acol] = make_uint4(p0, p1, p2, p3);
            unsigned int q0 = (unsigned int)f2bf(av2.x) | ((unsigned int)f2bf(av2.y) << 16);
            unsigned int q1 = (unsigned int)f2bf(av2.z) | ((unsigned int)f2bf(av2.w) << 16);
            unsigned int q2 = (unsigned int)f2bf(av3.x) | ((unsigned int)f2bf(av3.y) << 16);
            unsigned int q3 = (unsigned int)f2bf(av3.z) | ((unsigned int)f2bf(av3.w) << 16);
            *(uint4*)&As[arow1][acol] = make_uint4(q0, q1, q2, q3);
        }

        __syncthreads();   // drains vmcnt (global_load_lds) + lgkm before reads

        #pragma unroll
        for (int kk = 0; kk < 2; ++kk) {
            short8 af[4], bfr[4];
            #pragma unroll
            for (int m = 0; m < 4; ++m)
                af[m] = *(const short8*)&As[m * 16 + l15][kk * 32 + g * 8];
            #pragma unroll
            for (int n = 0; n < 4; ++n) {
                int r = wc + n * 16 + l15;
                int ch = (kk * 4 + g) ^ (r & 7);
                bfr[n] = *(const short8*)(Bs + r * 64 + ch * 8);
            }
            #pragma unroll
            for (int m = 0; m < 4; ++m)
                #pragma unroll
                for (int n = 0; n < 4; ++n)
                    acc[m][n] = __builtin_amdgcn_mfma_f32_16x16x32_bf16(af[m], bfr[n], acc[m][n], 0, 0, 0);
        }
    }

    // epilogue: C/D layout col=lane&15, row=(lane>>4)*4+reg  [verified m89/m91]
    #pragma unroll
    for (int n = 0; n < 4; ++n) {
        int col = n0 + wc + n * 16 + l15;
        float bv = bias[col];
        #pragma unroll
        for (int m = 0; m < 4; ++m) {
            #pragma unroll
            for (int j = 0; j < 4; ++j) {
                int row = m0 + m * 16 + g * 4 + j;
                float v = acc[m][n][j] + bv;
                if (PHI) v = (v > 0.0f) ? (v + 1.0f) : __expf(v);  // elu(x)+1
                Y[(size_t)row * DM + col] = f2bf(v);
            }
        }
    }
}

// ---- kv einsum + k_red: KV[b,h][d][e] = sum_s kh[b,s,h,d]*vh[b,s,h,e] ----
__global__ __launch_bounds__(256) void kv_kernel(const unsigned short* __restrict__ kh,
                                                 const unsigned short* __restrict__ vh,
                                                 float* __restrict__ kv,
                                                 float* __restrict__ kred) {
    __shared__ float khs[32][64];
    __shared__ float vhs[32][64];
    const int t = threadIdx.x;
    const int b = blockIdx.z, h = blockIdx.y;
    const int s0 = blockIdx.x * 512;
    const int d0 = (t >> 4) * 4;
    const int e0 = (t & 15) * 4;

    float acc[4][4] = {};
    float kr[4] = {};

    const size_t rowbase = (size_t)b * SEQ * DM + h * DEPTH;

    for (int sc = 0; sc < 512; sc += 32) {
        int s_i = t >> 3, p = t & 7;
        size_t off = rowbase + (size_t)(s0 + sc + s_i) * DM + p * 8;
        int4 kraw = *(const int4*)(kh + off);
        int4 vraw = *(const int4*)(vh + off);
        const unsigned short* kk = (const unsigned short*)&kraw;
        const unsigned short* vv = (const unsigned short*)&vraw;
        __syncthreads();
        #pragma unroll
        for (int q = 0; q < 8; ++q) khs[s_i][p * 8 + q] = bf2f(kk[q]);
        #pragma unroll
        for (int q = 0; q < 8; ++q) vhs[s_i][p * 8 + q] = bf2f(vv[q]);
        __syncthreads();
        #pragma unroll 8
        for (int si = 0; si < 32; ++si) {
            float4 k4 = *(const float4*)&khs[si][d0];
            float4 v4 = *(const float4*)&vhs[si][e0];
            float ka[4] = {k4.x, k4.y, k4.z, k4.w};
            float va[4] = {v4.x, v4.y, v4.z, v4.w};
            #pragma unroll
            for (int i = 0; i < 4; ++i) kr[i] += ka[i];
            #pragma unroll
            for (int i = 0; i < 4; ++i)
                #pragma unroll
                for (int j = 0; j < 4; ++j)
                    acc[i][j] += ka[i] * va[j];
        }
    }
    float* kvp = kv + (size_t)(b * HEADS + h) * (DEPTH * DEPTH);
    #pragma unroll
    for (int i = 0; i < 4; ++i)
        #pragma unroll
        for (int j = 0; j < 4; ++j)
            atomicAdd(&kvp[(d0 + i) * DEPTH + e0 + j], acc[i][j]);
    if (e0 == 0) {
        float* krp = kred + (b * HEADS + h) * DEPTH;
        #pragma unroll
        for (int i = 0; i < 4; ++i) atomicAdd(&krp[d0 + i], kr[i]);
    }
}

// ---- out: out[b,s,h,e] = (sum_d qh_d * KV[d][e]) / (sum_d qh_d * (kred_d+eps)) ----
__global__ __launch_bounds__(256) void out_kernel(const unsigned short* __restrict__ qh,
                                                  const float* __restrict__ kv,
                                                  const float* __restrict__ kred,
                                                  float* __restrict__ out) {
    __shared__ float kvs[DEPTH * DEPTH];
    __shared__ float krs[DEPTH];
    const int t = threadIdx.x;
    const int b = blockIdx.z, h = blockIdx.y;
    const int s = blockIdx.x * 256 + t;

    const float* kvp = kv + (size_t)(b * HEADS + h) * (DEPTH * DEPTH);
    #pragma unroll
    for (int j = 0; j < 4; ++j) {
        int f = t + 256 * j;
        *(float4*)&kvs[f * 4] = *(const float4*)&kvp[f * 4];
    }
    if (t < DEPTH) krs[t] = kred[(b * HEADS + h) * DEPTH + t] + 1e-8f;
    __syncthreads();

    const size_t qoff = ((size_t)b * SEQ + s) * DM + h * DEPTH;
    float4 acc[16] = {};
    float den = 0.0f;
    for (int dblk = 0; dblk < 8; ++dblk) {
        int4 qraw = *(const int4*)(qh + qoff + dblk * 8);
        const unsigned short* qq = (const unsigned short*)&qraw;
        #pragma unroll
        for (int dd = 0; dd < 8; ++dd) {
            int d = dblk * 8 + dd;
            float qd = bf2f(qq[dd]);
            den += qd * krs[d];
            #pragma unroll
            for (int e4 = 0; e4 < 16; ++e4) {
                float4 kvv = *(const float4*)&kvs[d * 64 + e4 * 4];
                acc[e4].x += qd * kvv.x; acc[e4].y += qd * kvv.y;
                acc[e4].z += qd * kvv.z; acc[e4].w += qd * kvv.w;
            }
        }
    }
    float z = 1.0f / den;
    float* op = out + qoff;
    #pragma unroll
    for (int e4 = 0; e4 < 16; ++e4) {
        float4 v = acc[e4];
        v.x *= z; v.y *= z; v.z *= z; v.w *= z;
        *(float4*)(op + e4 * 4) = v;
    }
}

extern "C" void kernel_launch(void* const* d_in, const int* in_sizes, int n_in,
                              void* d_out, int out_size, void* d_ws, size_t ws_size,
                              hipStream_t stream) {
    const float* q  = (const float*)d_in[0];
    const float* k  = (const float*)d_in[1];
    const float* v  = (const float*)d_in[2];
    const float* wq = (const float*)d_in[3];
    const float* bq = (const float*)d_in[4];
    const float* wk = (const float*)d_in[5];
    const float* bk = (const float*)d_in[6];
    const float* wv = (const float*)d_in[7];
    const float* bv = (const float*)d_in[8];
    float* out = (float*)d_out;

    char* ws = (char*)d_ws;
    const size_t sz_h = (size_t)MROWS * DM * 2;                 // 32 MiB each (bf16)
    unsigned short* qh  = (unsigned short*)(ws);
    unsigned short* kh  = (unsigned short*)(ws + sz_h);
    unsigned short* vh  = (unsigned short*)(ws + 2 * sz_h);
    unsigned short* wqT = (unsigned short*)(ws + 3 * sz_h);
    unsigned short* wkT = wqT + DM * DM;
    unsigned short* wvT = wkT + DM * DM;
    float* kvbuf   = (float*)(ws + 3 * sz_h + (size_t)3 * DM * DM * 2);
    float* kredbuf = kvbuf + BATCH * HEADS * DEPTH * DEPTH;

    hipMemsetAsync(kvbuf, 0,
                   (size_t)(BATCH * HEADS * DEPTH * DEPTH + BATCH * HEADS * DEPTH) * sizeof(float),
                   stream);

    wprep_kernel<<<dim3(DM * DM / 256), 256, 0, stream>>>(wq, wqT);
    wprep_kernel<<<dim3(DM * DM / 256), 256, 0, stream>>>(wk, wkT);
    wprep_kernel<<<dim3(DM * DM / 256), 256, 0, stream>>>(wv, wvT);

    dim3 pgrid(DM / 256, MROWS / 64);   // (2 n-blocks, 512 m-blocks)
    proj_kernel<1><<<pgrid, 256, 0, stream>>>(q, wqT, bq, qh);
    proj_kernel<1><<<pgrid, 256, 0, stream>>>(k, wkT, bk, kh);
    proj_kernel<0><<<pgrid, 256, 0, stream>>>(v, wvT, bv, vh);

    kv_kernel<<<dim3(16, HEADS, BATCH), 256, 0, stream>>>(kh, vh, kvbuf, kredbuf);
    out_kernel<<<dim3(SEQ / 256, HEADS, BATCH), 256, 0, stream>>>(qh, kvbuf, kredbuf, out);
}

// Round 3
// 228.873 us; speedup vs baseline: 1.3330x; 1.1462x over previous
//
#include <hip/hip_runtime.h>
#include <hip/hip_bf16.h>

#define DM 512
#define HEADS 8
#define DEPTH 64
#define BATCH 4
#define SEQ 8192
#define MROWS (BATCH*SEQ)

using short8 = __attribute__((ext_vector_type(8))) short;
using floatx4 = __attribute__((ext_vector_type(4))) float;

#define AS1 __attribute__((address_space(1)))
#define AS3 __attribute__((address_space(3)))

static __device__ __forceinline__ float bf2f(unsigned short u) {
    union { unsigned int i; float f; } x; x.i = ((unsigned int)u) << 16; return x.f;
}
static __device__ __forceinline__ unsigned short f2bf(float f) {
    union { float f; unsigned int i; } x; x.f = f;
    unsigned int i = x.i;
    return (unsigned short)((i + 0x7FFFu + ((i >> 16) & 1u)) >> 16);
}
static __device__ __forceinline__ void gl_lds16(const unsigned short* g, unsigned short* l) {
    __builtin_amdgcn_global_load_lds((const AS1 unsigned int*)g, (AS3 unsigned int*)l, 16, 0, 0);
}

// ---- W prep: transpose + convert to bf16. wT[n][k] = w[k][n] ----
__global__ __launch_bounds__(256) void wprep_kernel(const float* __restrict__ w,
                                                    unsigned short* __restrict__ wT) {
    int idx = blockIdx.x * 256 + threadIdx.x;
    int k = idx & (DM - 1);
    int n = idx >> 9;
    wT[n * DM + k] = f2bf(w[k * DM + n]);
}

// ---- Projection GEMM: Y[m][n] = phi?(X @ W + bias) as bf16 ----
// Tile 64(M) x 256(N), BK=64, 4 waves: wave w owns cols [w*64, w*64+64), all 64 rows.
template<int PHI>
__global__ __launch_bounds__(256) void proj_kernel(const float* __restrict__ X,
                                                   const unsigned short* __restrict__ WT,
                                                   const float* __restrict__ bias,
                                                   unsigned short* __restrict__ Y) {
    __shared__ unsigned short As[64][72];      // 9 KiB (144 B rows)
    __shared__ unsigned short Bs[256 * 64];    // 32 KiB (swizzled contents)

    const int t = threadIdx.x;
    const int l = t & 63;
    const int w = t >> 6;
    const int l15 = l & 15;
    const int g = l >> 4;
    const int m0 = blockIdx.y * 64;
    const int n0 = blockIdx.x * 256;
    const int wc = w * 64;

    const int arow0 = t >> 3;
    const int arow1 = 32 + (t >> 3);
    const int acol = (t & 7) * 8;
    const float* xp0 = X + (size_t)(m0 + arow0) * DM + acol;
    const float* xp1 = X + (size_t)(m0 + arow1) * DM + acol;

    floatx4 acc[4][4] = {};

    for (int k0 = 0; k0 < DM; k0 += 64) {
        const float4 av0 = *(const float4*)(xp0 + k0);
        const float4 av1 = *(const float4*)(xp0 + k0 + 4);
        const float4 av2 = *(const float4*)(xp1 + k0);
        const float4 av3 = *(const float4*)(xp1 + k0 + 4);

        __syncthreads();

        #pragma unroll
        for (int i = 0; i < 8; ++i) {
            int c = i * 256 + t;
            int r = c >> 3;
            int gp = c & 7;
            int gd = gp ^ (r & 7);
            const unsigned short* gsrc = WT + (size_t)(n0 + r) * DM + k0 + gd * 8;
            unsigned short* ldst = Bs + ((size_t)i * 256 + w * 64) * 8;
            gl_lds16(gsrc, ldst);
        }

        {
            unsigned int p0 = (unsigned int)f2bf(av0.x) | ((unsigned int)f2bf(av0.y) << 16);
            unsigned int p1 = (unsigned int)f2bf(av0.z) | ((unsigned int)f2bf(av0.w) << 16);
            unsigned int p2 = (unsigned int)f2bf(av1.x) | ((unsigned int)f2bf(av1.y) << 16);
            unsigned int p3 = (unsigned int)f2bf(av1.z) | ((unsigned int)f2bf(av1.w) << 16);
            *(uint4*)&As[arow0][acol] = make_uint4(p0, p1, p2, p3);
            unsigned int q0 = (unsigned int)f2bf(av2.x) | ((unsigned int)f2bf(av2.y) << 16);
            unsigned int q1 = (unsigned int)f2bf(av2.z) | ((unsigned int)f2bf(av2.w) << 16);
            unsigned int q2 = (unsigned int)f2bf(av3.x) | ((unsigned int)f2bf(av3.y) << 16);
            unsigned int q3 = (unsigned int)f2bf(av3.z) | ((unsigned int)f2bf(av3.w) << 16);
            *(uint4*)&As[arow1][acol] = make_uint4(q0, q1, q2, q3);
        }

        __syncthreads();

        #pragma unroll
        for (int kk = 0; kk < 2; ++kk) {
            short8 af[4], bfr[4];
            #pragma unroll
            for (int m = 0; m < 4; ++m)
                af[m] = *(const short8*)&As[m * 16 + l15][kk * 32 + g * 8];
            #pragma unroll
            for (int n = 0; n < 4; ++n) {
                int r = wc + n * 16 + l15;
                int ch = (kk * 4 + g) ^ (r & 7);
                bfr[n] = *(const short8*)(Bs + r * 64 + ch * 8);
            }
            #pragma unroll
            for (int m = 0; m < 4; ++m)
                #pragma unroll
                for (int n = 0; n < 4; ++n)
                    acc[m][n] = __builtin_amdgcn_mfma_f32_16x16x32_bf16(af[m], bfr[n], acc[m][n], 0, 0, 0);
        }
    }

    #pragma unroll
    for (int n = 0; n < 4; ++n) {
        int col = n0 + wc + n * 16 + l15;
        float bv = bias[col];
        #pragma unroll
        for (int m = 0; m < 4; ++m) {
            #pragma unroll
            for (int j = 0; j < 4; ++j) {
                int row = m0 + m * 16 + g * 4 + j;
                float v = acc[m][n][j] + bv;
                if (PHI) v = (v > 0.0f) ? (v + 1.0f) : __expf(v);  // elu(x)+1
                Y[(size_t)row * DM + col] = f2bf(v);
            }
        }
    }
}

// ---- kv einsum + k_red ----
__global__ __launch_bounds__(256) void kv_kernel(const unsigned short* __restrict__ kh,
                                                 const unsigned short* __restrict__ vh,
                                                 float* __restrict__ kv,
                                                 float* __restrict__ kred) {
    __shared__ float khs[32][64];
    __shared__ float vhs[32][64];
    const int t = threadIdx.x;
    const int b = blockIdx.z, h = blockIdx.y;
    const int s0 = blockIdx.x * 512;
    const int d0 = (t >> 4) * 4;
    const int e0 = (t & 15) * 4;

    float acc[4][4] = {};
    float kr[4] = {};

    const size_t rowbase = (size_t)b * SEQ * DM + h * DEPTH;

    for (int sc = 0; sc < 512; sc += 32) {
        int s_i = t >> 3, p = t & 7;
        size_t off = rowbase + (size_t)(s0 + sc + s_i) * DM + p * 8;
        int4 kraw = *(const int4*)(kh + off);
        int4 vraw = *(const int4*)(vh + off);
        const unsigned short* kk = (const unsigned short*)&kraw;
        const unsigned short* vv = (const unsigned short*)&vraw;
        __syncthreads();
        #pragma unroll
        for (int q = 0; q < 8; ++q) khs[s_i][p * 8 + q] = bf2f(kk[q]);
        #pragma unroll
        for (int q = 0; q < 8; ++q) vhs[s_i][p * 8 + q] = bf2f(vv[q]);
        __syncthreads();
        #pragma unroll 8
        for (int si = 0; si < 32; ++si) {
            float4 k4 = *(const float4*)&khs[si][d0];
            float4 v4 = *(const float4*)&vhs[si][e0];
            float ka[4] = {k4.x, k4.y, k4.z, k4.w};
            float va[4] = {v4.x, v4.y, v4.z, v4.w};
            #pragma unroll
            for (int i = 0; i < 4; ++i) kr[i] += ka[i];
            #pragma unroll
            for (int i = 0; i < 4; ++i)
                #pragma unroll
                for (int j = 0; j < 4; ++j)
                    acc[i][j] += ka[i] * va[j];
        }
    }
    float* kvp = kv + (size_t)(b * HEADS + h) * (DEPTH * DEPTH);
    #pragma unroll
    for (int i = 0; i < 4; ++i)
        #pragma unroll
        for (int j = 0; j < 4; ++j)
            atomicAdd(&kvp[(d0 + i) * DEPTH + e0 + j], acc[i][j]);
    if (e0 == 0) {
        float* krp = kred + (b * HEADS + h) * DEPTH;
        #pragma unroll
        for (int i = 0; i < 4; ++i) atomicAdd(&krp[d0 + i], kr[i]);
    }
}

// ---- out via MFMA: per (b,h): out[s][e] = (qh[s][:] @ KV[:][e]) / (qh[s][:] @ (kred+eps)) ----
// Block: 256 s-rows, 4 waves (wave w = rows w*64..w*64+63). K=64 single step.
// A (qh) staged swizzled via global_load_lds (proj-B pattern); B = KVT bf16 [80][72] padded LDS:
//   rows 0..63 = KV^T (e-major), row 64 = kred+eps (den column), rows 65..79 = 0.
__global__ __launch_bounds__(256) void out_kernel(const unsigned short* __restrict__ qh,
                                                  const float* __restrict__ kv,
                                                  const float* __restrict__ kred,
                                                  float* __restrict__ out) {
    __shared__ unsigned short Qs[256 * 64];    // 32 KiB, chunk-XOR swizzled
    __shared__ unsigned short KVTs[80][72];    // 11.25 KiB, pad-72 (2-way alias = free)

    const int t = threadIdx.x;
    const int l = t & 63;
    const int w = t >> 6;
    const int l15 = l & 15;
    const int g = l >> 4;
    const int b = blockIdx.z, h = blockIdx.y;
    const int s0 = blockIdx.x * 256;
    const int wr = w * 64;

    // stage qh tile: 256 rows x 64 d, chunk-XOR pre-swizzled global source
    const size_t qbase = ((size_t)b * SEQ + s0) * DM + h * DEPTH;
    #pragma unroll
    for (int i = 0; i < 8; ++i) {
        int c = i * 256 + t;
        int r = c >> 3;
        int gp = c & 7;
        int gd = gp ^ (r & 7);
        const unsigned short* gsrc = qh + qbase + (size_t)r * DM + gd * 8;
        unsigned short* ldst = Qs + ((size_t)i * 256 + w * 64) * 8;
        gl_lds16(gsrc, ldst);
    }

    // stage KVT: kvts[e][d] = bf16(KV[d][e]); row 64 = kred+eps; rows 65..79 = 0
    const float* kvp = kv + (size_t)(b * HEADS + h) * (DEPTH * DEPTH);
    const float* krp = kred + (size_t)(b * HEADS + h) * DEPTH;
    #pragma unroll
    for (int j = 0; j < 20; ++j) {
        int f = j * 256 + t;
        int e = f >> 6, d = f & 63;
        float val = (e < 64) ? kvp[d * DEPTH + e]
                  : (e == 64 ? (krp[d] + 1e-8f) : 0.0f);
        KVTs[e][d] = f2bf(val);
    }

    __syncthreads();   // drains global_load_lds (vmcnt) + LDS writes

    short8 af[2][4], bfr[2][5];
    #pragma unroll
    for (int kk = 0; kk < 2; ++kk) {
        #pragma unroll
        for (int m = 0; m < 4; ++m) {
            int r = wr + m * 16 + l15;
            int ch = (kk * 4 + g) ^ (r & 7);
            af[kk][m] = *(const short8*)(Qs + r * 64 + ch * 8);
        }
        #pragma unroll
        for (int n = 0; n < 5; ++n)
            bfr[kk][n] = *(const short8*)&KVTs[n * 16 + l15][kk * 32 + g * 8];
    }

    floatx4 acc[4][5] = {};
    #pragma unroll
    for (int kk = 0; kk < 2; ++kk)
        #pragma unroll
        for (int m = 0; m < 4; ++m)
            #pragma unroll
            for (int n = 0; n < 5; ++n)
                acc[m][n] = __builtin_amdgcn_mfma_f32_16x16x32_bf16(af[kk][m], bfr[kk][n], acc[m][n], 0, 0, 0);

    // epilogue: den = acc[m][4] col 0 (lane l15==0); broadcast within 16-lane group
    float* op = out + ((size_t)b * SEQ + s0) * DM + h * DEPTH;
    #pragma unroll
    for (int m = 0; m < 4; ++m) {
        #pragma unroll
        for (int j = 0; j < 4; ++j) {
            float den = __shfl(acc[m][4][j], l & 48);
            float z = 1.0f / den;
            int row = wr + m * 16 + g * 4 + j;
            #pragma unroll
            for (int n = 0; n < 4; ++n)
                op[(size_t)row * DM + n * 16 + l15] = acc[m][n][j] * z;
        }
    }
}

extern "C" void kernel_launch(void* const* d_in, const int* in_sizes, int n_in,
                              void* d_out, int out_size, void* d_ws, size_t ws_size,
                              hipStream_t stream) {
    const float* q  = (const float*)d_in[0];
    const float* k  = (const float*)d_in[1];
    const float* v  = (const float*)d_in[2];
    const float* wq = (const float*)d_in[3];
    const float* bq = (const float*)d_in[4];
    const float* wk = (const float*)d_in[5];
    const float* bk = (const float*)d_in[6];
    const float* wv = (const float*)d_in[7];
    const float* bv = (const float*)d_in[8];
    float* out = (float*)d_out;

    char* ws = (char*)d_ws;
    const size_t sz_h = (size_t)MROWS * DM * 2;                 // 32 MiB each (bf16)
    unsigned short* qh  = (unsigned short*)(ws);
    unsigned short* kh  = (unsigned short*)(ws + sz_h);
    unsigned short* vh  = (unsigned short*)(ws + 2 * sz_h);
    unsigned short* wqT = (unsigned short*)(ws + 3 * sz_h);
    unsigned short* wkT = wqT + DM * DM;
    unsigned short* wvT = wkT + DM * DM;
    float* kvbuf   = (float*)(ws + 3 * sz_h + (size_t)3 * DM * DM * 2);
    float* kredbuf = kvbuf + BATCH * HEADS * DEPTH * DEPTH;

    hipMemsetAsync(kvbuf, 0,
                   (size_t)(BATCH * HEADS * DEPTH * DEPTH + BATCH * HEADS * DEPTH) * sizeof(float),
                   stream);

    wprep_kernel<<<dim3(DM * DM / 256), 256, 0, stream>>>(wq, wqT);
    wprep_kernel<<<dim3(DM * DM / 256), 256, 0, stream>>>(wk, wkT);
    wprep_kernel<<<dim3(DM * DM / 256), 256, 0, stream>>>(wv, wvT);

    dim3 pgrid(DM / 256, MROWS / 64);
    proj_kernel<1><<<pgrid, 256, 0, stream>>>(q, wqT, bq, qh);
    proj_kernel<1><<<pgrid, 256, 0, stream>>>(k, wkT, bk, kh);
    proj_kernel<0><<<pgrid, 256, 0, stream>>>(v, wvT, bv, vh);

    kv_kernel<<<dim3(16, HEADS, BATCH), 256, 0, stream>>>(kh, vh, kvbuf, kredbuf);
    out_kernel<<<dim3(SEQ / 256, HEADS, BATCH), 256, 0, stream>>>(qh, kvbuf, kredbuf, out);
}

// Round 4
// 199.766 us; speedup vs baseline: 1.5272x; 1.1457x over previous
//
#include <hip/hip_runtime.h>
#include <hip/hip_bf16.h>

#define DM 512
#define HEADS 8
#define DEPTH 64
#define BATCH 4
#define SEQ 8192
#define MROWS (BATCH*SEQ)

using short8 = __attribute__((ext_vector_type(8))) short;
using floatx4 = __attribute__((ext_vector_type(4))) float;

#define AS1 __attribute__((address_space(1)))
#define AS3 __attribute__((address_space(3)))

static __device__ __forceinline__ float bf2f(unsigned short u) {
    union { unsigned int i; float f; } x; x.i = ((unsigned int)u) << 16; return x.f;
}
static __device__ __forceinline__ unsigned short f2bf(float f) {
    union { float f; unsigned int i; } x; x.f = f;
    unsigned int i = x.i;
    return (unsigned short)((i + 0x7FFFu + ((i >> 16) & 1u)) >> 16);
}
static __device__ __forceinline__ void gl_lds16(const unsigned short* g, unsigned short* l) {
    __builtin_amdgcn_global_load_lds((const AS1 unsigned int*)g, (AS3 unsigned int*)l, 16, 0, 0);
}

// ---- W prep: transpose + convert to bf16. wT[n][k] = w[k][n] ----
__global__ __launch_bounds__(256) void wprep_kernel(const float* __restrict__ w,
                                                    unsigned short* __restrict__ wT) {
    int idx = blockIdx.x * 256 + threadIdx.x;
    int k = idx & (DM - 1);
    int n = idx >> 9;
    wT[n * DM + k] = f2bf(w[k * DM + n]);
}

// ---- Projection GEMM: Y[m][n] = phi?(X @ W + bias) as bf16 ----
// Tile 64(M) x 256(N), BK=64, 4 waves: wave w owns cols [w*64, w*64+64), all 64 rows.
template<int PHI>
__global__ __launch_bounds__(256) void proj_kernel(const float* __restrict__ X,
                                                   const unsigned short* __restrict__ WT,
                                                   const float* __restrict__ bias,
                                                   unsigned short* __restrict__ Y) {
    __shared__ unsigned short As[64][72];      // 9 KiB (144 B rows)
    __shared__ unsigned short Bs[256 * 64];    // 32 KiB (swizzled contents)

    const int t = threadIdx.x;
    const int l = t & 63;
    const int w = t >> 6;
    const int l15 = l & 15;
    const int g = l >> 4;
    const int m0 = blockIdx.y * 64;
    const int n0 = blockIdx.x * 256;
    const int wc = w * 64;

    const int arow0 = t >> 3;
    const int arow1 = 32 + (t >> 3);
    const int acol = (t & 7) * 8;
    const float* xp0 = X + (size_t)(m0 + arow0) * DM + acol;
    const float* xp1 = X + (size_t)(m0 + arow1) * DM + acol;

    floatx4 acc[4][4] = {};

    for (int k0 = 0; k0 < DM; k0 += 64) {
        const float4 av0 = *(const float4*)(xp0 + k0);
        const float4 av1 = *(const float4*)(xp0 + k0 + 4);
        const float4 av2 = *(const float4*)(xp1 + k0);
        const float4 av3 = *(const float4*)(xp1 + k0 + 4);

        __syncthreads();

        #pragma unroll
        for (int i = 0; i < 8; ++i) {
            int c = i * 256 + t;
            int r = c >> 3;
            int gp = c & 7;
            int gd = gp ^ (r & 7);
            const unsigned short* gsrc = WT + (size_t)(n0 + r) * DM + k0 + gd * 8;
            unsigned short* ldst = Bs + ((size_t)i * 256 + w * 64) * 8;
            gl_lds16(gsrc, ldst);
        }

        {
            unsigned int p0 = (unsigned int)f2bf(av0.x) | ((unsigned int)f2bf(av0.y) << 16);
            unsigned int p1 = (unsigned int)f2bf(av0.z) | ((unsigned int)f2bf(av0.w) << 16);
            unsigned int p2 = (unsigned int)f2bf(av1.x) | ((unsigned int)f2bf(av1.y) << 16);
            unsigned int p3 = (unsigned int)f2bf(av1.z) | ((unsigned int)f2bf(av1.w) << 16);
            *(uint4*)&As[arow0][acol] = make_uint4(p0, p1, p2, p3);
            unsigned int q0 = (unsigned int)f2bf(av2.x) | ((unsigned int)f2bf(av2.y) << 16);
            unsigned int q1 = (unsigned int)f2bf(av2.z) | ((unsigned int)f2bf(av2.w) << 16);
            unsigned int q2 = (unsigned int)f2bf(av3.x) | ((unsigned int)f2bf(av3.y) << 16);
            unsigned int q3 = (unsigned int)f2bf(av3.z) | ((unsigned int)f2bf(av3.w) << 16);
            *(uint4*)&As[arow1][acol] = make_uint4(q0, q1, q2, q3);
        }

        __syncthreads();

        #pragma unroll
        for (int kk = 0; kk < 2; ++kk) {
            short8 af[4], bfr[4];
            #pragma unroll
            for (int m = 0; m < 4; ++m)
                af[m] = *(const short8*)&As[m * 16 + l15][kk * 32 + g * 8];
            #pragma unroll
            for (int n = 0; n < 4; ++n) {
                int r = wc + n * 16 + l15;
                int ch = (kk * 4 + g) ^ (r & 7);
                bfr[n] = *(const short8*)(Bs + r * 64 + ch * 8);
            }
            #pragma unroll
            for (int m = 0; m < 4; ++m)
                #pragma unroll
                for (int n = 0; n < 4; ++n)
                    acc[m][n] = __builtin_amdgcn_mfma_f32_16x16x32_bf16(af[m], bfr[n], acc[m][n], 0, 0, 0);
        }
    }

    #pragma unroll
    for (int n = 0; n < 4; ++n) {
        int col = n0 + wc + n * 16 + l15;
        float bv = bias[col];
        #pragma unroll
        for (int m = 0; m < 4; ++m) {
            #pragma unroll
            for (int j = 0; j < 4; ++j) {
                int row = m0 + m * 16 + g * 4 + j;
                float v = acc[m][n][j] + bv;
                if (PHI) v = (v > 0.0f) ? (v + 1.0f) : __expf(v);  // elu(x)+1
                Y[(size_t)row * DM + col] = f2bf(v);
            }
        }
    }
}

// ---- kv einsum + k_red via MFMA ----
// Per (b,h): KV[d][e] = sum_s kh[s][d]*vh[s][e]. Block = 256 s-rows, K-tiles of 32.
// Transpose-on-stage: coalesced int4 global reads (one s, 8 d) scattered as 8
// ds_write_b16 into khT/vhT [64][40] (80B rows keep b128 frag reads 16B-aligned).
// Wave w owns d-rows [w*16, w*16+16): A=1 frag, B=4 frags + ones-frag for kred.
#define KV_CHUNK 256
#define KV_TILE 32
__global__ __launch_bounds__(256) void kv_kernel(const unsigned short* __restrict__ kh,
                                                 const unsigned short* __restrict__ vh,
                                                 float* __restrict__ kv,
                                                 float* __restrict__ kred) {
    __shared__ unsigned short khT[64][40];
    __shared__ unsigned short vhT[64][40];

    const int t = threadIdx.x;
    const int w = t >> 6;
    const int l15 = t & 15;
    const int g = (t >> 4) & 3;
    const int b = blockIdx.z, h = blockIdx.y;
    const int s0 = blockIdx.x * KV_CHUNK;

    const int s_i = t >> 3;          // 0..31 within tile
    const int d0 = (t & 7) * 8;

    const size_t gbase = ((size_t)b * SEQ + s0 + s_i) * DM + h * DEPTH + d0;

    short8 ones;
    #pragma unroll
    for (int i = 0; i < 8; ++i) ones[i] = (short)0x3F80;  // bf16 1.0

    floatx4 acc[5] = {};

    // prologue: load tile 0 into regs
    int4 kr = *(const int4*)(kh + gbase);
    int4 vr = *(const int4*)(vh + gbase);

    #pragma unroll
    for (int tile = 0; tile < KV_CHUNK / KV_TILE; ++tile) {
        // scatter current regs -> transposed LDS (compiler waits vmcnt before use)
        {
            const unsigned short* kk = (const unsigned short*)&kr;
            const unsigned short* vv = (const unsigned short*)&vr;
            #pragma unroll
            for (int i = 0; i < 8; ++i) khT[d0 + i][s_i] = kk[i];
            #pragma unroll
            for (int i = 0; i < 8; ++i) vhT[d0 + i][s_i] = vv[i];
        }
        // prefetch next tile (overlaps MFMA phase)
        if (tile + 1 < KV_CHUNK / KV_TILE) {
            size_t off = gbase + (size_t)(tile + 1) * KV_TILE * DM;
            kr = *(const int4*)(kh + off);
            vr = *(const int4*)(vh + off);
        }
        __syncthreads();

        short8 af = *(const short8*)&khT[w * 16 + l15][g * 8];
        short8 bf0 = *(const short8*)&vhT[0 * 16 + l15][g * 8];
        short8 bf1 = *(const short8*)&vhT[1 * 16 + l15][g * 8];
        short8 bf2 = *(const short8*)&vhT[2 * 16 + l15][g * 8];
        short8 bf3 = *(const short8*)&vhT[3 * 16 + l15][g * 8];
        acc[0] = __builtin_amdgcn_mfma_f32_16x16x32_bf16(af, bf0, acc[0], 0, 0, 0);
        acc[1] = __builtin_amdgcn_mfma_f32_16x16x32_bf16(af, bf1, acc[1], 0, 0, 0);
        acc[2] = __builtin_amdgcn_mfma_f32_16x16x32_bf16(af, bf2, acc[2], 0, 0, 0);
        acc[3] = __builtin_amdgcn_mfma_f32_16x16x32_bf16(af, ones, acc[3], 0, 0, 0);
        acc[4] = __builtin_amdgcn_mfma_f32_16x16x32_bf16(af, bf3, acc[4], 0, 0, 0);
        __syncthreads();
    }

    // epilogue: C/D layout col=lane&15, row=(lane>>4)*4+reg
    float* kvp = kv + (size_t)(b * HEADS + h) * (DEPTH * DEPTH);
    #pragma unroll
    for (int j = 0; j < 4; ++j) {
        int drow = w * 16 + g * 4 + j;
        atomicAdd(&kvp[drow * DEPTH + 0 * 16 + l15], acc[0][j]);
        atomicAdd(&kvp[drow * DEPTH + 1 * 16 + l15], acc[1][j]);
        atomicAdd(&kvp[drow * DEPTH + 2 * 16 + l15], acc[2][j]);
        atomicAdd(&kvp[drow * DEPTH + 3 * 16 + l15], acc[4][j]);
    }
    if (l15 == 0) {
        float* krp = kred + (b * HEADS + h) * DEPTH;
        #pragma unroll
        for (int j = 0; j < 4; ++j)
            atomicAdd(&krp[w * 16 + g * 4 + j], acc[3][j]);
    }
}

// ---- out via MFMA: per (b,h): out[s][e] = (qh[s][:] @ KV[:][e]) / (qh[s][:] @ (kred+eps)) ----
__global__ __launch_bounds__(256) void out_kernel(const unsigned short* __restrict__ qh,
                                                  const float* __restrict__ kv,
                                                  const float* __restrict__ kred,
                                                  float* __restrict__ out) {
    __shared__ unsigned short Qs[256 * 64];    // 32 KiB, chunk-XOR swizzled
    __shared__ unsigned short KVTs[80][72];    // pad-72 (2-way alias = free)

    const int t = threadIdx.x;
    const int l = t & 63;
    const int w = t >> 6;
    const int l15 = l & 15;
    const int g = l >> 4;
    const int b = blockIdx.z, h = blockIdx.y;
    const int s0 = blockIdx.x * 256;
    const int wr = w * 64;

    const size_t qbase = ((size_t)b * SEQ + s0) * DM + h * DEPTH;
    #pragma unroll
    for (int i = 0; i < 8; ++i) {
        int c = i * 256 + t;
        int r = c >> 3;
        int gp = c & 7;
        int gd = gp ^ (r & 7);
        const unsigned short* gsrc = qh + qbase + (size_t)r * DM + gd * 8;
        unsigned short* ldst = Qs + ((size_t)i * 256 + w * 64) * 8;
        gl_lds16(gsrc, ldst);
    }

    const float* kvp = kv + (size_t)(b * HEADS + h) * (DEPTH * DEPTH);
    const float* krp = kred + (size_t)(b * HEADS + h) * DEPTH;
    #pragma unroll
    for (int j = 0; j < 20; ++j) {
        int f = j * 256 + t;
        int e = f >> 6, d = f & 63;
        float val = (e < 64) ? kvp[d * DEPTH + e]
                  : (e == 64 ? (krp[d] + 1e-8f) : 0.0f);
        KVTs[e][d] = f2bf(val);
    }

    __syncthreads();

    short8 af[2][4], bfr[2][5];
    #pragma unroll
    for (int kk = 0; kk < 2; ++kk) {
        #pragma unroll
        for (int m = 0; m < 4; ++m) {
            int r = wr + m * 16 + l15;
            int ch = (kk * 4 + g) ^ (r & 7);
            af[kk][m] = *(const short8*)(Qs + r * 64 + ch * 8);
        }
        #pragma unroll
        for (int n = 0; n < 5; ++n)
            bfr[kk][n] = *(const short8*)&KVTs[n * 16 + l15][kk * 32 + g * 8];
    }

    floatx4 acc[4][5] = {};
    #pragma unroll
    for (int kk = 0; kk < 2; ++kk)
        #pragma unroll
        for (int m = 0; m < 4; ++m)
            #pragma unroll
            for (int n = 0; n < 5; ++n)
                acc[m][n] = __builtin_amdgcn_mfma_f32_16x16x32_bf16(af[kk][m], bfr[kk][n], acc[m][n], 0, 0, 0);

    float* op = out + ((size_t)b * SEQ + s0) * DM + h * DEPTH;
    #pragma unroll
    for (int m = 0; m < 4; ++m) {
        #pragma unroll
        for (int j = 0; j < 4; ++j) {
            float den = __shfl(acc[m][4][j], l & 48);
            float z = 1.0f / den;
            int row = wr + m * 16 + g * 4 + j;
            #pragma unroll
            for (int n = 0; n < 4; ++n)
                op[(size_t)row * DM + n * 16 + l15] = acc[m][n][j] * z;
        }
    }
}

extern "C" void kernel_launch(void* const* d_in, const int* in_sizes, int n_in,
                              void* d_out, int out_size, void* d_ws, size_t ws_size,
                              hipStream_t stream) {
    const float* q  = (const float*)d_in[0];
    const float* k  = (const float*)d_in[1];
    const float* v  = (const float*)d_in[2];
    const float* wq = (const float*)d_in[3];
    const float* bq = (const float*)d_in[4];
    const float* wk = (const float*)d_in[5];
    const float* bk = (const float*)d_in[6];
    const float* wv = (const float*)d_in[7];
    const float* bv = (const float*)d_in[8];
    float* out = (float*)d_out;

    char* ws = (char*)d_ws;
    const size_t sz_h = (size_t)MROWS * DM * 2;                 // 32 MiB each (bf16)
    unsigned short* qh  = (unsigned short*)(ws);
    unsigned short* kh  = (unsigned short*)(ws + sz_h);
    unsigned short* vh  = (unsigned short*)(ws + 2 * sz_h);
    unsigned short* wqT = (unsigned short*)(ws + 3 * sz_h);
    unsigned short* wkT = wqT + DM * DM;
    unsigned short* wvT = wkT + DM * DM;
    float* kvbuf   = (float*)(ws + 3 * sz_h + (size_t)3 * DM * DM * 2);
    float* kredbuf = kvbuf + BATCH * HEADS * DEPTH * DEPTH;

    hipMemsetAsync(kvbuf, 0,
                   (size_t)(BATCH * HEADS * DEPTH * DEPTH + BATCH * HEADS * DEPTH) * sizeof(float),
                   stream);

    wprep_kernel<<<dim3(DM * DM / 256), 256, 0, stream>>>(wq, wqT);
    wprep_kernel<<<dim3(DM * DM / 256), 256, 0, stream>>>(wk, wkT);
    wprep_kernel<<<dim3(DM * DM / 256), 256, 0, stream>>>(wv, wvT);

    dim3 pgrid(DM / 256, MROWS / 64);
    proj_kernel<1><<<pgrid, 256, 0, stream>>>(q, wqT, bq, qh);
    proj_kernel<1><<<pgrid, 256, 0, stream>>>(k, wkT, bk, kh);
    proj_kernel<0><<<pgrid, 256, 0, stream>>>(v, wvT, bv, vh);

    kv_kernel<<<dim3(SEQ / KV_CHUNK, HEADS, BATCH), 256, 0, stream>>>(kh, vh, kvbuf, kredbuf);
    out_kernel<<<dim3(SEQ / 256, HEADS, BATCH), 256, 0, stream>>>(qh, kvbuf, kredbuf, out);
}